// Round 1
// baseline (353.145 us; speedup 1.0000x reference)
//
#include <hip/hip_runtime.h>
#include <hip/hip_bf16.h>

// Problem constants (features: (16, 1024, 512) fp32)
#define B_ 16
#define T_ 1024
#define D_ 512
#define INV_TEMP 14.285714285714286f   // 1/0.07
#define EPS_ 1e-8f

#define BM 64
#define BN 64
#define BK 16
#define JSPAN 256      // columns handled per block (T_/JSPAN = 4 z-splits)
#define PAD 4          // LDS padding (keeps 16B alignment, kills write conflicts)

// ---------------- zero-init (ws + out are poisoned 0xAA every launch) --------
__global__ void zero_kernel(float* __restrict__ rs_g, float* __restrict__ rp_g,
                            float* __restrict__ out) {
    const int i = blockIdx.x * 256 + threadIdx.x;
    if (i < B_ * T_) { rs_g[i] = 0.0f; rp_g[i] = 0.0f; }
    if (i == 0) out[0] = 0.0f;
}

// ---------------- row L2-normalize: one wave per row -------------------------
__global__ __launch_bounds__(256) void norm_kernel(const float* __restrict__ f,
                                                   float* __restrict__ nrm) {
    const int row  = blockIdx.x * 4 + (threadIdx.x >> 6);
    const int lane = threadIdx.x & 63;
    const size_t off = (size_t)row * D_ + lane * 8;
    const float4 v0 = *(const float4*)(f + off);
    const float4 v1 = *(const float4*)(f + off + 4);
    float ss = v0.x*v0.x + v0.y*v0.y + v0.z*v0.z + v0.w*v0.w
             + v1.x*v1.x + v1.y*v1.y + v1.z*v1.z + v1.w*v1.w;
    #pragma unroll
    for (int o = 32; o >= 1; o >>= 1) ss += __shfl_xor(ss, o, 64);
    const float sc = 1.0f / fmaxf(sqrtf(ss), EPS_);
    float4 w0, w1;
    w0.x = v0.x*sc; w0.y = v0.y*sc; w0.z = v0.z*sc; w0.w = v0.w*sc;
    w1.x = v1.x*sc; w1.y = v1.y*sc; w1.z = v1.z*sc; w1.w = v1.w*sc;
    *(float4*)(nrm + off)     = w0;
    *(float4*)(nrm + off + 4) = w1;
}

// ---------------- fused sim-GEMM + masked exp row-reduction ------------------
// grid: (T_/BM, B_, T_/JSPAN); block: 256.
// Each block: rows [t0, t0+64) x cols [jbase, jbase+256), K = 512.
// Accumulates partial sum_neg exp(logit) and pos logit per (b,t) into ws.
__global__ __launch_bounds__(256) void loss_kernel(const float* __restrict__ nrm,
                                                   float* __restrict__ rs_g,
                                                   float* __restrict__ rp_g) {
    const int b     = blockIdx.y;
    const int t0    = blockIdx.x * BM;
    const int jbase = blockIdx.z * JSPAN;
    const float* base = nrm + (size_t)b * T_ * D_;

    __shared__ float As[BK][BM + PAD];
    __shared__ float Bs[BK][BN + PAD];

    const int tid = threadIdx.x;
    const int tx  = tid & 15;        // column group (4 cols each)
    const int ty  = tid >> 4;        // row group    (4 rows each)
    const int lm  = tid >> 2;        // staging: row within tile (0..63)
    const int lk  = (tid & 3) * 4;   // staging: k offset (0,4,8,12)

    float rs[4] = {0.f, 0.f, 0.f, 0.f};   // partial sum of exp over negatives
    float rp[4] = {0.f, 0.f, 0.f, 0.f};   // pos logit (exactly one writer)

    for (int j0 = jbase; j0 < jbase + JSPAN; j0 += BN) {
        float acc[4][4] = {};
        for (int k0 = 0; k0 < D_; k0 += BK) {
            const float4 av = *(const float4*)(base + (size_t)(t0 + lm) * D_ + k0 + lk);
            const float4 bv = *(const float4*)(base + (size_t)(j0 + lm) * D_ + k0 + lk);
            __syncthreads();
            As[lk+0][lm] = av.x; As[lk+1][lm] = av.y; As[lk+2][lm] = av.z; As[lk+3][lm] = av.w;
            Bs[lk+0][lm] = bv.x; Bs[lk+1][lm] = bv.y; Bs[lk+2][lm] = bv.z; Bs[lk+3][lm] = bv.w;
            __syncthreads();
            #pragma unroll
            for (int k = 0; k < BK; ++k) {
                const float4 a  = *(const float4*)(&As[k][ty * 4]);
                const float4 bb = *(const float4*)(&Bs[k][tx * 4]);
                acc[0][0] += a.x*bb.x; acc[0][1] += a.x*bb.y; acc[0][2] += a.x*bb.z; acc[0][3] += a.x*bb.w;
                acc[1][0] += a.y*bb.x; acc[1][1] += a.y*bb.y; acc[1][2] += a.y*bb.z; acc[1][3] += a.y*bb.w;
                acc[2][0] += a.z*bb.x; acc[2][1] += a.z*bb.y; acc[2][2] += a.z*bb.z; acc[2][3] += a.z*bb.w;
                acc[3][0] += a.w*bb.x; acc[3][1] += a.w*bb.y; acc[3][2] += a.w*bb.z; acc[3][3] += a.w*bb.w;
            }
        }
        // epilogue: logits -> masked exp sums + pos capture
        #pragma unroll
        for (int r = 0; r < 4; ++r) {
            const int t = t0 + ty * 4 + r;
            #pragma unroll
            for (int c = 0; c < 4; ++c) {
                const int j = j0 + tx * 4 + c;
                const float s = acc[r][c] * INV_TEMP;
                const float e = __expf(s);
                if (j < t - 1 || j > t + 1) rs[r] += e;   // negatives only
                if (j == t + 1)             rp[r] = s;    // positive logit
            }
        }
    }

    // reduce across the 16 tx lanes sharing each row (lane bits 0..3)
    #pragma unroll
    for (int r = 0; r < 4; ++r) {
        #pragma unroll
        for (int o = 8; o >= 1; o >>= 1) {
            rs[r] += __shfl_xor(rs[r], o, 64);
            rp[r] += __shfl_xor(rp[r], o, 64);
        }
    }
    if (tx == 0) {
        #pragma unroll
        for (int r = 0; r < 4; ++r) {
            const int t = t0 + ty * 4 + r;
            atomicAdd(&rs_g[b * T_ + t], rs[r]);
            atomicAdd(&rp_g[b * T_ + t], rp[r]);
        }
    }
}

// ---------------- finalize: loss per (b,t), mean -----------------------------
__global__ __launch_bounds__(256) void fin_kernel(const float* __restrict__ rs_g,
                                                  const float* __restrict__ rp_g,
                                                  float* __restrict__ out) {
    const int idx = blockIdx.x * 256 + threadIdx.x;
    float v = 0.0f;
    if (idx < B_ * T_) {
        const int t = idx & (T_ - 1);
        if (t >= 1 && t <= T_ - 2) {
            const float pos  = rp_g[idx];
            const float sneg = rs_g[idx];
            v = logf(__expf(pos) + sneg) - pos;   // logaddexp(pos, lse_neg) - pos
        }
    }
    #pragma unroll
    for (int o = 32; o >= 1; o >>= 1) v += __shfl_xor(v, o, 64);
    __shared__ float ws_[4];
    if ((threadIdx.x & 63) == 0) ws_[threadIdx.x >> 6] = v;
    __syncthreads();
    if (threadIdx.x == 0) {
        const float scale = 1.0f / (float)(B_ * (T_ - 2));
        atomicAdd(out, (ws_[0] + ws_[1] + ws_[2] + ws_[3]) * scale);
    }
}

extern "C" void kernel_launch(void* const* d_in, const int* in_sizes, int n_in,
                              void* d_out, int out_size, void* d_ws, size_t ws_size,
                              hipStream_t stream) {
    const float* feat = (const float*)d_in[0];
    float* out = (float*)d_out;

    float* ws   = (float*)d_ws;
    float* nrm  = ws;                          // B*T*D floats (32 MB)
    float* rs_g = ws + (size_t)B_ * T_ * D_;   // B*T floats
    float* rp_g = rs_g + B_ * T_;              // B*T floats

    zero_kernel<<<(B_ * T_ + 255) / 256, 256, 0, stream>>>(rs_g, rp_g, out);
    norm_kernel<<<B_ * T_ / 4, 256, 0, stream>>>(feat, nrm);
    loss_kernel<<<dim3(T_ / BM, B_, T_ / JSPAN), 256, 0, stream>>>(nrm, rs_g, rp_g);
    fin_kernel<<<(B_ * T_ + 255) / 256, 256, 0, stream>>>(rs_g, rp_g, out);
}

// Round 2
// 114.435 us; speedup vs baseline: 3.0860x; 3.0860x over previous
//
#include <hip/hip_runtime.h>
#include <hip/hip_bf16.h>

// Problem constants (features: (16, 1024, 512) fp32)
#define B_ 16
#define T_ 1024
#define D_ 512
#define INV_TEMP 14.285714285714286f   // 1/0.07
#define EPS_ 1e-8f

// MFMA GEMM tile (m97-verified structure)
#define BM 128
#define BN 128
#define BKK 32          // bf16 K per iteration
#define NKIT (D_ / BKK) // 16 K-iterations

typedef __attribute__((ext_vector_type(8))) short short8;   // 8 bf16 = 4 VGPRs
typedef __attribute__((ext_vector_type(4))) float floatx4;

typedef __attribute__((address_space(1))) const unsigned int g_u32;
typedef __attribute__((address_space(3))) unsigned int l_u32;

__device__ __forceinline__ void glds16(const void* g, void* l) {
    __builtin_amdgcn_global_load_lds((g_u32*)g, (l_u32*)l, 16, 0, 0);
}

__device__ __forceinline__ unsigned short f2bf(float x) {
    unsigned u = __float_as_uint(x);
    return (unsigned short)((u + 0x7fffu + ((u >> 16) & 1u)) >> 16);  // RNE
}

// ---------------- zero-init (ws + out are poisoned 0xAA every launch) --------
__global__ void zero_kernel(float* __restrict__ rs_g, float* __restrict__ rp_g,
                            float* __restrict__ out) {
    const int i = blockIdx.x * 256 + threadIdx.x;
    if (i < B_ * T_) { rs_g[i] = 0.0f; rp_g[i] = 0.0f; }
    if (i == 0) out[0] = 0.0f;
}

// ---------------- row L2-normalize -> bf16: one wave per row -----------------
__global__ __launch_bounds__(256) void norm_kernel(const float* __restrict__ f,
                                                   unsigned short* __restrict__ nrm) {
    const int row  = blockIdx.x * 4 + (threadIdx.x >> 6);
    const int lane = threadIdx.x & 63;
    const size_t off = (size_t)row * D_ + lane * 8;
    const float4 v0 = *(const float4*)(f + off);
    const float4 v1 = *(const float4*)(f + off + 4);
    float ss = v0.x*v0.x + v0.y*v0.y + v0.z*v0.z + v0.w*v0.w
             + v1.x*v1.x + v1.y*v1.y + v1.z*v1.z + v1.w*v1.w;
    #pragma unroll
    for (int o = 32; o >= 1; o >>= 1) ss += __shfl_xor(ss, o, 64);
    const float sc = 1.0f / fmaxf(sqrtf(ss), EPS_);
    ushort4 w0, w1;
    w0.x = f2bf(v0.x*sc); w0.y = f2bf(v0.y*sc); w0.z = f2bf(v0.z*sc); w0.w = f2bf(v0.w*sc);
    w1.x = f2bf(v1.x*sc); w1.y = f2bf(v1.y*sc); w1.z = f2bf(v1.z*sc); w1.w = f2bf(v1.w*sc);
    *(ushort4*)(nrm + off)     = w0;
    *(ushort4*)(nrm + off + 4) = w1;
}

// ---------------- MFMA sim-GEMM + masked exp row-reduction -------------------
// grid: (T_/BM, B_, T_/BN); block 256 = 4 waves.
// Block computes C tile rows [t0,t0+128) x cols [j0,j0+128), K=512 bf16.
// Wave (wr,wc) owns the 64x64 quadrant; 4x4 grid of 16x16x32 MFMAs.
__global__ __launch_bounds__(256) void loss_kernel(const unsigned short* __restrict__ nrm,
                                                   float* __restrict__ rs_g,
                                                   float* __restrict__ rp_g) {
    const int b  = blockIdx.y;
    const int t0 = blockIdx.x * BM;
    const int j0 = blockIdx.z * BN;
    const char* base = (const char*)(nrm + (size_t)b * T_ * D_);  // row stride 1024 B

    __shared__ __align__(16) unsigned short As[BM * BKK];  // [128][32] row-major, 8 KB
    __shared__ __align__(16) unsigned short Bs[BN * BKK];  // [128][32] row-major, 8 KB

    const int tid  = threadIdx.x;
    const int w    = tid >> 6;
    const int lane = tid & 63;
    const int wr   = w >> 1;         // quadrant row (0..1)
    const int wc   = w & 1;          // quadrant col (0..1)
    const int m    = lane & 15;      // MFMA row/col-in-fragment lane
    const int kq   = lane >> 4;      // k-block (0..3) -> k = kq*8 + j

    // staging: 8 KB tile = 8 wave-calls of 1 KB; wave w does calls (2w, 2w+1)
    const int o0 = (w * 2 + 0) * 1024 + lane * 16;   // byte offset in tile
    const int o1 = (w * 2 + 1) * 1024 + lane * 16;
    const char* gA0 = base + (size_t)(t0 + (o0 >> 6)) * 1024 + (o0 & 63);
    const char* gA1 = base + (size_t)(t0 + (o1 >> 6)) * 1024 + (o1 & 63);
    const char* gB0 = base + (size_t)(j0 + (o0 >> 6)) * 1024 + (o0 & 63);
    const char* gB1 = base + (size_t)(j0 + (o1 >> 6)) * 1024 + (o1 & 63);
    char* lA0 = (char*)As + (w * 2 + 0) * 1024;   // wave-uniform LDS base (+lane*16 by HW)
    char* lA1 = (char*)As + (w * 2 + 1) * 1024;
    char* lB0 = (char*)Bs + (w * 2 + 0) * 1024;
    char* lB1 = (char*)Bs + (w * 2 + 1) * 1024;

    floatx4 acc[4][4] = {};

    for (int kit = 0; kit < NKIT; ++kit) {
        const int kb = kit * 64;   // byte offset of k0 within a row
        glds16(gA0 + kb, lA0);
        glds16(gA1 + kb, lA1);
        glds16(gB0 + kb, lB0);
        glds16(gB1 + kb, lB1);
        __syncthreads();   // drains vmcnt: staging visible

        short8 a[4], bf[4];
        #pragma unroll
        for (int mi = 0; mi < 4; ++mi)
            a[mi] = *(const short8*)(As + (wr * 64 + mi * 16 + m) * BKK + kq * 8);
        #pragma unroll
        for (int ni = 0; ni < 4; ++ni)
            bf[ni] = *(const short8*)(Bs + (wc * 64 + ni * 16 + m) * BKK + kq * 8);

        #pragma unroll
        for (int mi = 0; mi < 4; ++mi)
            #pragma unroll
            for (int ni = 0; ni < 4; ++ni)
                acc[mi][ni] = __builtin_amdgcn_mfma_f32_16x16x32_bf16(
                    a[mi], bf[ni], acc[mi][ni], 0, 0, 0);

        __syncthreads();   // protect LDS from next iteration's staging
    }

    // Epilogue. C/D layout (m89-verified): col = lane&15, row = (lane>>4)*4 + reg.
    const int lrow = lane >> 4;
    const int lcol = lane & 15;
    #pragma unroll
    for (int mi = 0; mi < 4; ++mi) {
        #pragma unroll
        for (int r = 0; r < 4; ++r) {
            const int t = t0 + wr * 64 + mi * 16 + lrow * 4 + r;
            float rs = 0.0f, rp = 0.0f;
            #pragma unroll
            for (int ni = 0; ni < 4; ++ni) {
                const int j = j0 + wc * 64 + ni * 16 + lcol;
                const float s = acc[mi][ni][r] * INV_TEMP;
                const float e = __expf(s);
                if (j < t - 1 || j > t + 1) rs += e;   // negatives only
                if (j == t + 1)             rp  = s;   // positive logit
            }
            // reduce across the 16 column lanes (lane bits 0..3)
            #pragma unroll
            for (int o = 8; o >= 1; o >>= 1) {
                rs += __shfl_xor(rs, o, 64);
                rp += __shfl_xor(rp, o, 64);
            }
            if (lcol == 0) {
                atomicAdd(&rs_g[b * T_ + t], rs);
                atomicAdd(&rp_g[b * T_ + t], rp);
            }
        }
    }
}

// ---------------- finalize: loss per (b,t), mean -----------------------------
__global__ __launch_bounds__(256) void fin_kernel(const float* __restrict__ rs_g,
                                                  const float* __restrict__ rp_g,
                                                  float* __restrict__ out) {
    const int idx = blockIdx.x * 256 + threadIdx.x;
    float v = 0.0f;
    if (idx < B_ * T_) {
        const int t = idx & (T_ - 1);
        if (t >= 1 && t <= T_ - 2) {
            const float pos  = rp_g[idx];
            const float sneg = rs_g[idx];
            v = logf(__expf(pos) + sneg) - pos;   // logaddexp(pos, lse_neg) - pos
        }
    }
    #pragma unroll
    for (int o = 32; o >= 1; o >>= 1) v += __shfl_xor(v, o, 64);
    __shared__ float ws_[4];
    if ((threadIdx.x & 63) == 0) ws_[threadIdx.x >> 6] = v;
    __syncthreads();
    if (threadIdx.x == 0) {
        const float scale = 1.0f / (float)(B_ * (T_ - 2));
        atomicAdd(out, (ws_[0] + ws_[1] + ws_[2] + ws_[3]) * scale);
    }
}

extern "C" void kernel_launch(void* const* d_in, const int* in_sizes, int n_in,
                              void* d_out, int out_size, void* d_ws, size_t ws_size,
                              hipStream_t stream) {
    const float* feat = (const float*)d_in[0];
    float* out = (float*)d_out;

    // ws layout: nrm (bf16, B*T*D ushorts = 16 MB) | rs (B*T f32) | rp (B*T f32)
    unsigned short* nrm = (unsigned short*)d_ws;
    float* rs_g = (float*)((char*)d_ws + (size_t)B_ * T_ * D_ * sizeof(unsigned short));
    float* rp_g = rs_g + B_ * T_;

    zero_kernel<<<(B_ * T_ + 255) / 256, 256, 0, stream>>>(rs_g, rp_g, out);
    norm_kernel<<<B_ * T_ / 4, 256, 0, stream>>>(feat, nrm);
    loss_kernel<<<dim3(T_ / BM, B_, T_ / BN), 256, 0, stream>>>(nrm, rs_g, rp_g);
    fin_kernel<<<(B_ * T_ + 255) / 256, 256, 0, stream>>>(rs_g, rp_g, out);
}